// Round 2
// baseline (174.004 us; speedup 1.0000x reference)
//
#include <hip/hip_runtime.h>

// Problem constants (derived from in_sizes at launch; these are the expected values)
//   x        : (B, C, 7, 7) fp32      -> in[0], B*C*49
//   s        : (B, 1, 56, 56) fp32    -> in[1], B*3136
//   feat_mask: (8, 7, 7) fp32         -> in[2], 392
//   sal_idx  : (8, N) int32           -> in[3], 8*N  (N = 406)
// out = [feat (B*C*8) | sal_feat (B*N*8)] fp32

#define ROWS_PER_BLOCK 256
#define KPIX 49

__global__ __launch_bounds__(256) void mdp_fused_kernel(
    const float* __restrict__ x, const float* __restrict__ s,
    const float* __restrict__ fm, const int* __restrict__ sidx,
    float* __restrict__ out, int BC, int nb1, int N, int SHW)
{
    const int tid = threadIdx.x;
    if ((int)blockIdx.x < nb1) {
        // ---- feat path: 256 rows of 49 pixels per block ----
        __shared__ float xs[ROWS_PER_BLOCK * KPIX];   // 49 KB
        __shared__ float ms[8 * KPIX];
        __shared__ float cnt[8];

        const int r0 = blockIdx.x * ROWS_PER_BLOCK;
        const int nrows = min(ROWS_PER_BLOCK, BC - r0);

        // BUGFIX R1: 8*KPIX=392 > blockDim(256); previous single-shot load
        // left ms[256..391] uninitialized -> garbage masks for p>=5.
        for (int i = tid; i < 8 * KPIX; i += 256) ms[i] = fm[i];

        if (nrows == ROWS_PER_BLOCK) {
            // full tile: vectorized coalesced staging (base is 16B aligned:
            // r0*49*4 = blockIdx*50176, 50176 % 16 == 0)
            const float4* xg = (const float4*)(x + (size_t)r0 * KPIX);
            float4* xs4 = (float4*)xs;
            const int nfl4 = (ROWS_PER_BLOCK * KPIX) / 4;  // 3136
            #pragma unroll 4
            for (int i = tid; i < nfl4; i += 256) xs4[i] = xg[i];
        } else {
            const int nfl = nrows * KPIX;
            const float* xg = x + (size_t)r0 * KPIX;
            for (int i = tid; i < nfl; i += 256) xs[i] = xg[i];
        }
        __syncthreads();

        if (tid < 8) {
            float c = 0.f;
            for (int k = 0; k < KPIX; ++k)
                c += (ms[tid * KPIX + k] != 0.f) ? 1.f : 0.f;
            cnt[tid] = c;
        }
        __syncthreads();

        const int r = r0 + tid;
        if (r < BC) {
            const float* row = &xs[tid * KPIX];  // stride 49 (odd) -> conflict-free
            float sum[8];
            #pragma unroll
            for (int p = 0; p < 8; ++p) sum[p] = 0.f;
            #pragma unroll
            for (int k = 0; k < KPIX; ++k) {
                const float v = row[k];
                #pragma unroll
                for (int p = 0; p < 8; ++p) sum[p] += v * ms[p * KPIX + k];
            }
            float* o = out + (size_t)r * 8;
            #pragma unroll
            for (int p = 0; p < 8; ++p) o[p] = sum[p] / cnt[p];
        }
    } else {
        // ---- sal_feat path: one block per batch ----
        const int b = blockIdx.x - nb1;
        const float* srow = s + (size_t)b * SHW;
        float* o2 = out + (size_t)BC * 8 + (size_t)b * N * 8;
        const int tot = N * 8;
        for (int i = tid; i < tot; i += 256) {
            const int p = i & 7;
            const int n = i >> 3;
            o2[i] = srow[sidx[p * N + n]];  // writes coalesced; gather hits L1/L2
        }
    }
}

extern "C" void kernel_launch(void* const* d_in, const int* in_sizes, int n_in,
                              void* d_out, int out_size, void* d_ws, size_t ws_size,
                              hipStream_t stream) {
    const float* x    = (const float*)d_in[0];
    const float* s    = (const float*)d_in[1];
    const float* fm   = (const float*)d_in[2];
    const int*   sidx = (const int*)d_in[3];
    float* out = (float*)d_out;

    const int SHW = 3136;                  // 56*56 (s spatial)
    const int B   = in_sizes[1] / SHW;     // 256
    const int BC  = in_sizes[0] / KPIX;    // B*C = 524288
    const int N   = in_sizes[3] / 8;       // 406

    const int nb1 = (BC + ROWS_PER_BLOCK - 1) / ROWS_PER_BLOCK;  // 2048
    const int grid = nb1 + B;

    mdp_fused_kernel<<<grid, 256, 0, stream>>>(x, s, fm, sidx, out, BC, nb1, N, SHW);
}

// Round 4
// 171.533 us; speedup vs baseline: 1.0144x; 1.0144x over previous
//
#include <hip/hip_runtime.h>

//   x        : (B, C, 7, 7) fp32      -> in[0], B*C*49
//   s        : (B, 1, 56, 56) fp32    -> in[1], B*3136
//   feat_mask: (8, 7, 7) fp32         -> in[2], 392
//   sal_idx  : (8, N) int32           -> in[3], 8*N  (N = 406)
// out = [feat (B*C*8) | sal_feat (B*N*8)] fp32

#define ROWS_PER_BLOCK 256
#define KPIX 49

__global__ __launch_bounds__(256) void mdp_fused_kernel(
    const float* __restrict__ x, const float* __restrict__ s,
    const float* __restrict__ fm, const int* __restrict__ sidx,
    float* __restrict__ out, int BC, int nb1, int N, int SHW)
{
    const int tid = threadIdx.x;
    if ((int)blockIdx.x < nb1) {
        // ---- feat path: 256 rows of 49 pixels per block ----
        __shared__ float xs[ROWS_PER_BLOCK * KPIX];   // 49 KB
        __shared__ float rcnt[8];                     // 1/count per direction

        const int r0 = blockIdx.x * ROWS_PER_BLOCK;
        const int nrows = min(ROWS_PER_BLOCK, BC - r0);

        // counts: 8 lanes, tiny reads, once per block (covered by the barrier below)
        if (tid < 8) {
            float c = 0.f;
            for (int k = 0; k < KPIX; ++k)
                c += (fm[tid * KPIX + k] != 0.f) ? 1.f : 0.f;
            rcnt[tid] = 1.0f / c;
        }

        if (nrows == ROWS_PER_BLOCK) {
            // full tile: coalesced float4 staging (base 16B aligned: blk*50176)
            const float4* xg = (const float4*)(x + (size_t)r0 * KPIX);
            float4* xs4 = (float4*)xs;
            const int nfl4 = (ROWS_PER_BLOCK * KPIX) / 4;  // 3136
            #pragma unroll 4
            for (int i = tid; i < nfl4; i += 256) xs4[i] = xg[i];
        } else {
            const int nfl = nrows * KPIX;
            const float* xg = x + (size_t)r0 * KPIX;
            for (int i = tid; i < nfl; i += 256) xs[i] = xg[i];
        }
        __syncthreads();

        const int r = r0 + tid;
        if (r < BC) {
            // row -> registers; stride 49 (odd) => bank-conflict-free b32 reads
            const float* rowp = &xs[tid * KPIX];
            float row[KPIX];
            #pragma unroll
            for (int k = 0; k < KPIX; ++k) row[k] = rowp[k];

            float rc[8];
            #pragma unroll
            for (int p = 0; p < 8; ++p) rc[p] = rcnt[p];  // LDS broadcast, 8 reads

            // mask reads are wave-uniform from readonly kernarg -> s_load into
            // SGPRs; FMA uses the SGPR operand (no LDS traffic).
            float sum[8];   // single array (R3 bug: aliasing two float4 locals was UB)
            #pragma unroll
            for (int p = 0; p < 8; ++p) {
                float acc = 0.f;
                #pragma unroll
                for (int k = 0; k < KPIX; ++k)
                    acc += row[k] * fm[p * KPIX + k];
                sum[p] = acc * rc[p];
            }
            // two coalesced 16B stores (out + r*8 is 32B aligned)
            float4* o = (float4*)(out + (size_t)r * 8);
            o[0] = make_float4(sum[0], sum[1], sum[2], sum[3]);
            o[1] = make_float4(sum[4], sum[5], sum[6], sum[7]);
        }
    } else {
        // ---- sal_feat path: one block per batch ----
        const int b = blockIdx.x - nb1;
        const float* srow = s + (size_t)b * SHW;
        float* o2 = out + (size_t)BC * 8 + (size_t)b * N * 8;
        const int tot = N * 8;
        for (int i = tid; i < tot; i += 256) {
            const int p = i & 7;
            const int n = i >> 3;
            o2[i] = srow[sidx[p * N + n]];  // writes coalesced; gather hits L1/L2
        }
    }
}

extern "C" void kernel_launch(void* const* d_in, const int* in_sizes, int n_in,
                              void* d_out, int out_size, void* d_ws, size_t ws_size,
                              hipStream_t stream) {
    const float* x    = (const float*)d_in[0];
    const float* s    = (const float*)d_in[1];
    const float* fm   = (const float*)d_in[2];
    const int*   sidx = (const int*)d_in[3];
    float* out = (float*)d_out;

    const int SHW = 3136;                  // 56*56 (s spatial)
    const int B   = in_sizes[1] / SHW;     // 256
    const int BC  = in_sizes[0] / KPIX;    // B*C = 524288
    const int N   = in_sizes[3] / 8;       // 406

    const int nb1 = (BC + ROWS_PER_BLOCK - 1) / ROWS_PER_BLOCK;  // 2048
    const int grid = nb1 + B;

    mdp_fused_kernel<<<grid, 256, 0, stream>>>(x, s, fm, sidx, out, BC, nb1, N, SHW);
}

// Round 5
// 166.361 us; speedup vs baseline: 1.0459x; 1.0311x over previous
//
#include <hip/hip_runtime.h>

//   x        : (B, C, 7, 7) fp32      -> in[0], B*C*49
//   s        : (B, 1, 56, 56) fp32    -> in[1], B*3136
//   feat_mask: (8, 7, 7) fp32         -> in[2], 392
//   sal_idx  : (8, N) int32           -> in[3], 8*N  (N = 406)
// out = [feat (B*C*8) | sal_feat (B*N*8)] fp32
//
// R5 structure: one-wave (64-thread) workgroups. 12.4 KB LDS/block -> ~12
// blocks/CU resident vs R4's 2; no multi-wave barrier coupling. R2->R4 showed
// the bottleneck is latency exposure, not LDS/VALU issue.

#define KPIX 49
#define TROWS 64
#define TFLOATS (TROWS * KPIX)   // 3136
#define TF4 (TFLOATS / 4)        // 784 = 12*64 + 16

__global__ __launch_bounds__(64, 3) void mdp_fused_kernel(
    const float* __restrict__ x, const float* __restrict__ s,
    const float* __restrict__ fm, const int* __restrict__ sidx,
    float* __restrict__ out, int BC, int nb1, int N, int SHW, int qper)
{
    const int lane = threadIdx.x;

    if ((int)blockIdx.x < nb1) {
        // ---- feat path: one wave, 64 rows ----
        __shared__ float xs[TFLOATS];
        const int r0 = blockIdx.x * TROWS;

        // per-direction 1/count via ballot (stays in SGPRs; no extra pass)
        float rc[8];
        #pragma unroll
        for (int p = 0; p < 8; ++p) {
            float v = (lane < KPIX) ? fm[p * KPIX + lane] : 0.f;
            unsigned long long bm = __ballot(v != 0.f);
            rc[p] = 1.0f / (float)__popcll(bm);
        }

        // stage 64 rows (3136 floats) coalesced; base 16B aligned (blk*12544)
        const float4* xg = (const float4*)(x + (size_t)r0 * KPIX);
        float4* xs4 = (float4*)xs;
        if (r0 + TROWS <= BC) {
            #pragma unroll
            for (int j = 0; j < 12; ++j) xs4[j * 64 + lane] = xg[j * 64 + lane];
            if (lane < 16) xs4[768 + lane] = xg[768 + lane];
        } else {
            const int nfl = (BC - r0) * KPIX;
            const float* xgs = x + (size_t)r0 * KPIX;
            for (int i = lane; i < nfl; i += 64) xs[i] = xgs[i];
        }
        __syncthreads();   // single wave: just a waitcnt drain, no cross-wave stall

        const int r = r0 + lane;
        if (r < BC) {
            float row[KPIX];   // stride-49 LDS reads: 2-way bank alias = free
            #pragma unroll
            for (int k = 0; k < KPIX; ++k) row[k] = xs[lane * KPIX + k];

            float sum[8];
            #pragma unroll
            for (int p = 0; p < 8; ++p) {
                float acc = 0.f;
                #pragma unroll
                for (int k = 0; k < KPIX; ++k)
                    acc += row[k] * fm[p * KPIX + k];   // uniform addr -> s_load/L1 broadcast
                sum[p] = acc * rc[p];
            }
            float4* o = (float4*)(out + (size_t)r * 8);
            o[0] = make_float4(sum[0], sum[1], sum[2], sum[3]);
            o[1] = make_float4(sum[4], sum[5], sum[6], sum[7]);
        }
    } else {
        // ---- sal_feat path: qper blocks per batch row (short latency chains) ----
        const int bq = blockIdx.x - nb1;
        const int b = bq / qper, q = bq % qper;
        const int tot = N * 8;
        const int chunk = tot / qper;
        const float* srow = s + (size_t)b * SHW;
        float* o2 = out + (size_t)BC * 8 + (size_t)b * tot + (size_t)q * chunk;
        for (int i = lane; i < chunk; i += 64) {
            const int e = q * chunk + i;
            o2[i] = srow[sidx[(e & 7) * N + (e >> 3)]];
        }
    }
}

extern "C" void kernel_launch(void* const* d_in, const int* in_sizes, int n_in,
                              void* d_out, int out_size, void* d_ws, size_t ws_size,
                              hipStream_t stream) {
    const float* x    = (const float*)d_in[0];
    const float* s    = (const float*)d_in[1];
    const float* fm   = (const float*)d_in[2];
    const int*   sidx = (const int*)d_in[3];
    float* out = (float*)d_out;

    const int SHW = 3136;                  // 56*56
    const int B   = in_sizes[1] / SHW;     // 256
    const int BC  = in_sizes[0] / KPIX;    // 524288
    const int N   = in_sizes[3] / 8;       // 406

    const int nb1  = (BC + TROWS - 1) / TROWS;          // 8192
    const int qper = ((N * 8) % 4 == 0) ? 4 : 1;        // 812-elem chunks
    const int grid = nb1 + B * qper;                    // 8192 + 1024

    mdp_fused_kernel<<<grid, 64, 0, stream>>>(x, s, fm, sidx, out,
                                              BC, nb1, N, SHW, qper);
}